// Round 9
// baseline (243.285 us; speedup 1.0000x reference)
//
#include <hip/hip_runtime.h>

// Reduced problem: out[n] depends only on x0 = node_vec[:, :128], emb, W1_l0[:, :, :128],
// b1[:128], W2, b2, W3, b3, W4, b4.  y1/y2/gates are dead code in the reference.
//
// R8 -> R9: COUNTER-CAPTURE ROUND. R8 structure, whole body repeated 4x inside
// the kernel (idempotent) so the main dispatch (~65 us) outlasts the ~44 us
// harness fills and surfaces in the rocprof top-5 WITH counters. Decision next
// round per VALUBusy / MfmaUtil / LDS_CONFLICT / FETCH_SIZE.

typedef _Float16 h8 __attribute__((ext_vector_type(8)));
typedef _Float16 h2 __attribute__((ext_vector_type(2)));
typedef float    f32x4 __attribute__((ext_vector_type(4)));
typedef unsigned int u32;

static __device__ __forceinline__ u32 pack2h(float a, float b) {
    h2 t = {(_Float16)a, (_Float16)b};
    return __builtin_bit_cast(u32, t);
}
static __device__ __forceinline__ f32x4 mfma_h(uint4 a, uint4 b, f32x4 c) {
    return __builtin_amdgcn_mfma_f32_16x16x32_f16(
        __builtin_bit_cast(h8, a), __builtin_bit_cast(h8, b), c, 0, 0, 0);
}
// A-frag element j = xh * ee[j];  covers k = q*8 + j for this lane's quad
static __device__ __forceinline__ uint4 mk_afrag(_Float16 xh, const h2* ee) {
    h2 xx = {xh, xh};
    uint4 r;
    r.x = __builtin_bit_cast(u32, (h2)(xx * ee[0]));
    r.y = __builtin_bit_cast(u32, (h2)(xx * ee[1]));
    r.z = __builtin_bit_cast(u32, (h2)(xx * ee[2]));
    r.w = __builtin_bit_cast(u32, (h2)(xx * ee[3]));
    return r;
}

// ---------------------------------------------------------------------------
// Prep: W1_l0 (keep cols 0..127) and W2 -> f16 B-fragment order:
//   W1T[kc][t][lane][j] = f16(W1[K = kc*32 + (lane>>4)*8 + j][t*16 + (lane&15)])
//   W2T[kc][lane][j]    = f16(W2[K][lane&15])
// ---------------------------------------------------------------------------
__global__ __launch_bounds__(256) void prep_kernel(
        const float* __restrict__ W1, const float* __restrict__ W2,
        _Float16* __restrict__ W1T, _Float16* __restrict__ W2T) {
    const int b = blockIdx.x, kc = b >> 2, tp = b & 3;
    const int tid = threadIdx.x;
    __shared__ float l1[32 * 36];
    __shared__ float l2[32 * 20];

    {   // 32 rows x 32 cols sub-tile of W1 (cols tp*32 .. +32)
        int row = tid >> 3, c4 = tid & 7;
        float4 v = *(const float4*)(W1 + (size_t)(kc * 32 + row) * 224 + tp * 32 + c4 * 4);
        *(float4*)(l1 + row * 36 + c4 * 4) = v;
    }
    if (tp == 0 && tid < 128) {
        int row = tid >> 2, c4 = tid & 3;
        float4 v = *(const float4*)(W2 + (size_t)(kc * 32 + row) * 16 + c4 * 4);
        *(float4*)(l2 + row * 20 + c4 * 4) = v;
    }
    __syncthreads();

    if (tid < 128) {
        int tl = tid >> 6, t = tp * 2 + tl, lane = tid & 63;
        int q = lane >> 4, cc = lane & 15, colL = tl * 16 + cc;
        u32 w[4];
#pragma unroll
        for (int jj = 0; jj < 4; ++jj)
            w[jj] = pack2h(l1[(q * 8 + 2 * jj) * 36 + colL],
                           l1[(q * 8 + 2 * jj + 1) * 36 + colL]);
        *(uint4*)(W1T + (size_t)kc * 4096 + (t * 64 + lane) * 8) =
            make_uint4(w[0], w[1], w[2], w[3]);
    }
    if (tp == 0 && tid >= 128 && tid < 192) {
        int lane = tid - 128, q = lane >> 4, cc = lane & 15;
        u32 w[4];
#pragma unroll
        for (int jj = 0; jj < 4; ++jj)
            w[jj] = pack2h(l2[(q * 8 + 2 * jj) * 20 + cc],
                           l2[(q * 8 + 2 * jj + 1) * 20 + cc]);
        *(uint4*)(W2T + (size_t)kc * 512 + lane * 8) = make_uint4(w[0], w[1], w[2], w[3]);
    }
}

// ---------------------------------------------------------------------------
// Main (R8 structure, x4 internal repeat for counter capture)
// ---------------------------------------------------------------------------
__global__ __launch_bounds__(1024) void main_kernel(
        const float* __restrict__ node_vec, const float* __restrict__ emb,
        const _Float16* __restrict__ W1T, const _Float16* __restrict__ W2T,
        const float* __restrict__ b1, const float* __restrict__ b2,
        const float* __restrict__ W3, const float* __restrict__ b3,
        const float* __restrict__ W4, const float* __restrict__ b4,
        float* __restrict__ out) {
    __shared__ __align__(16) _Float16 xsh[2 * 4608 + 8];  // even | pad | odd
    __shared__ __align__(16) char     uni[32768];  // p1 partials -> midp+mids
    __shared__ float w3s[256];
    __shared__ float b3s[16];
    __shared__ float w4s[16];
    __shared__ float b4s[1];

    _Float16* xe  = xsh;
    _Float16* xo  = xsh + 4608 + 8;
    float*    part = (float*)uni;                 // 128 cols x 64 nodes f32
    float*    midp = (float*)uni;                 // phase-2 partials
    float*    mids = (float*)(uni + 17408);

    const int tid  = threadIdx.x;
    const int wave = tid >> 6, lane = tid & 63;
    const int q = lane >> 4, c = lane & 15;
    const int ih = q >> 1;            // x-column parity this quad needs
    const int aodd = q & 1;           // emb half this quad needs
    const int nodeBase = blockIdx.x * 64;
    const float inv2048 = 0.022097086912079608f;   // 1/sqrt(128*16)

    for (int rep = 0; rep < 4; ++rep) {
        __syncthreads();   // prior repeat's reads of xe/xo/mids complete

        // stage x0 (cols 0..127), split even/odd k-columns, stride 72 halves
        for (int idx = tid; idx < 2048; idx += 1024) {
            int row = idx >> 5, c4 = idx & 31;
            float4 v = *(const float4*)(node_vec + (size_t)(nodeBase + row) * 480 + c4 * 4);
            h2 ev = {(_Float16)v.x, (_Float16)v.z};
            h2 ov = {(_Float16)v.y, (_Float16)v.w};
            *(h2*)(xe + row * 72 + c4 * 2) = ev;
            *(h2*)(xo + row * 72 + c4 * 2) = ov;
        }
        if (tid < 256) w3s[tid] = W3[tid];
        if (tid < 16) { b3s[tid] = b3[tid]; w4s[tid] = W4[tid]; }
        if (tid == 0) b4s[0] = b4[0];

        // per-lane emb slices for all 4 node-groups: node = nodeBase + g*16 + c
        h2 eeg[4][4];
#pragma unroll
        for (int g = 0; g < 4; ++g) {
            const float* ep = emb + (size_t)(nodeBase + g * 16 + c) * 16 + aodd * 8;
            float4 v0 = *(const float4*)ep;
            float4 v1 = *(const float4*)(ep + 4);
            eeg[g][0] = (h2){(_Float16)v0.x, (_Float16)v0.y};
            eeg[g][1] = (h2){(_Float16)v0.z, (_Float16)v0.w};
            eeg[g][2] = (h2){(_Float16)v1.x, (_Float16)v1.y};
            eeg[g][3] = (h2){(_Float16)v1.z, (_Float16)v1.w};
        }
        __syncthreads();

        // ---------------- Phase 1: 64 nodes x 16 cols x 32 K-steps per wave
        const int kh = wave >> 3;                     // K-half
        const int t  = wave & 7;                      // col-tile
        f32x4 acc[4];
#pragma unroll
        for (int g = 0; g < 4; ++g) acc[g] = (f32x4){0.f, 0.f, 0.f, 0.f};

        const uint4* bp = (const uint4*)W1T + t * 64 + lane + kh * 32 * 512;
        const _Float16* xb = (ih ? xo : xe) + kh * 32;
        const _Float16* xr0 = xb + (0 * 16 + c) * 72;
        const _Float16* xr1 = xb + (1 * 16 + c) * 72;
        const _Float16* xr2 = xb + (2 * 16 + c) * 72;
        const _Float16* xr3 = xb + (3 * 16 + c) * 72;

        uint4 ring[8];
#pragma unroll
        for (int r = 0; r < 8; ++r) ring[r] = bp[r * 512];
        h8 xcur[4], xnxt[4];
        xcur[0] = *(const h8*)xr0;       xcur[1] = *(const h8*)xr1;
        xcur[2] = *(const h8*)xr2;       xcur[3] = *(const h8*)xr3;
        xnxt[0] = *(const h8*)(xr0 + 8); xnxt[1] = *(const h8*)(xr1 + 8);
        xnxt[2] = *(const h8*)(xr2 + 8); xnxt[3] = *(const h8*)(xr3 + 8);

#pragma unroll
        for (int bb = 0; bb < 4; ++bb) {
#pragma unroll
            for (int u = 0; u < 8; ++u) {
                const int kl = bb * 8 + u;
                uint4 cur = ring[u];
                ring[u] = bp[(kl + 8) * 512];   // tail reads stay inside W1T+W2T
                acc[0] = mfma_h(mk_afrag(xcur[0][u], eeg[0]), cur, acc[0]);
                acc[1] = mfma_h(mk_afrag(xcur[1][u], eeg[1]), cur, acc[1]);
                acc[2] = mfma_h(mk_afrag(xcur[2][u], eeg[2]), cur, acc[2]);
                acc[3] = mfma_h(mk_afrag(xcur[3][u], eeg[3]), cur, acc[3]);
            }
            xcur[0] = xnxt[0]; xcur[1] = xnxt[1];
            xcur[2] = xnxt[2]; xcur[3] = xnxt[3];
            if (bb + 2 < 4) {
                const int o = (bb + 2) * 8;
                xnxt[0] = *(const h8*)(xr0 + o); xnxt[1] = *(const h8*)(xr1 + o);
                xnxt[2] = *(const h8*)(xr2 + o); xnxt[3] = *(const h8*)(xr3 + o);
            }
        }

        // kh=1 waves publish partials (part region untouched in phase 1)
        if (kh == 1) {
#pragma unroll
            for (int g = 0; g < 4; ++g)
                *(f32x4*)(part + (t * 16 + c) * 64 + g * 16 + q * 4) = acc[g];
        }
        __syncthreads();   // partials visible + all x reads done

        // kh=0 waves: reduce, silu -> f16 overlay of x. C layout: col=c, row=q*4+r.
        if (kh == 0) {
            float bb1v = b1[t * 16 + c];
            _Float16* dst = (c & 1) ? xo : xe;
            int colh = t * 8 + (c >> 1);
#pragma unroll
            for (int g = 0; g < 4; ++g) {
                f32x4 p = *(const f32x4*)(part + (t * 16 + c) * 64 + g * 16 + q * 4);
#pragma unroll
                for (int r = 0; r < 4; ++r) {
                    int node = g * 16 + q * 4 + r;
                    float s  = (acc[g][r] + p[r]) * inv2048 + bb1v;
                    float sc = s / (1.f + __expf(-s));
                    dst[node * 72 + colh] = (_Float16)sc;
                }
            }
        }
        __syncthreads();   // scs ready + part reads done (midp overlays part)

        // ---------------- Phase 2: (silu(s0) (x) emb) @ W2T
        {
            const int ng = wave >> 2, ks = wave & 3;
            const _Float16* srow = (ih ? xo : xe) + (ng * 16 + c) * 72 + ks * 16;
            h8 sa = *(const h8*)srow, sb = *(const h8*)(srow + 8);
            const uint4* b2p = (const uint4*)W2T + lane;
            f32x4 m0 = (f32x4){0.f, 0.f, 0.f, 0.f};
            uint4 wb[4];
#pragma unroll
            for (int u = 0; u < 4; ++u) wb[u] = b2p[(ks * 16 + u) * 64];
#pragma unroll
            for (int k2 = 0; k2 < 16; ++k2) {
                uint4 cur = wb[k2 & 3];
                if (k2 + 4 < 16) wb[k2 & 3] = b2p[(ks * 16 + k2 + 4) * 64];
                _Float16 sv = (k2 < 8) ? sa[k2] : sb[k2 - 8];
                m0 = mfma_h(mk_afrag(sv, eeg[ng]), cur, m0);
            }
#pragma unroll
            for (int r = 0; r < 4; ++r) {
                int node = ng * 16 + q * 4 + r;
                midp[(ks * 64 + node) * 17 + c] = m0[r];
            }
        }
        __syncthreads();

        // reduce 4 K-quarters; 1024 threads = 64 nodes x 16 cols
        {
            int node = tid >> 4, col = tid & 15;
            float m = midp[node * 17 + col] + midp[(64 + node) * 17 + col]
                    + midp[(128 + node) * 17 + col] + midp[(192 + node) * 17 + col];
            mids[node * 17 + col] = m * inv2048 + b2[col];
        }
        __syncthreads();

        // ---------------- Phase 3: h = silu(mid@W3/4 + b3); out = h@W4/4 + b4
        {
            int n = tid >> 4, jj = tid & 15;
            float a = 0.f;
#pragma unroll
            for (int cc = 0; cc < 16; ++cc) a += mids[n * 17 + cc] * w3s[cc * 16 + jj];
            a = a * 0.25f + b3s[jj];
            float hh = a / (1.f + __expf(-a));
            float po = hh * w4s[jj];
            po += __shfl_xor(po, 1);
            po += __shfl_xor(po, 2);
            po += __shfl_xor(po, 4);
            po += __shfl_xor(po, 8);
            if (jj == 0) out[nodeBase + n] = po * 0.25f + b4s[0];
        }
    }
}

extern "C" void kernel_launch(void* const* d_in, const int* in_sizes, int n_in,
                              void* d_out, int out_size, void* d_ws, size_t ws_size,
                              hipStream_t stream) {
    const float* node_vec = (const float*)d_in[0];
    const float* emb      = (const float*)d_in[1];
    const float* W1       = (const float*)d_in[2];
    const float* b1v      = (const float*)d_in[5];
    const float* W2       = (const float*)d_in[6];
    const float* b2v      = (const float*)d_in[7];
    const float* W3       = (const float*)d_in[8];
    const float* b3v      = (const float*)d_in[9];
    const float* W4       = (const float*)d_in[10];
    const float* b4v      = (const float*)d_in[11];

    _Float16* W1T = (_Float16*)d_ws;          // 64*4096 halves = 512 KB
    _Float16* W2T = W1T + 64 * 4096;          // 64*512  halves =  64 KB
    float* out = (float*)d_out;

    prep_kernel<<<256, 256, 0, stream>>>(W1, W2, W1T, W2T);
    main_kernel<<<256, 1024, 0, stream>>>(node_vec, emb, W1T, W2T,
                                          b1v, b2v, W3, b3v, W4, b4v, out);
}

// Round 10
// 113.261 us; speedup vs baseline: 2.1480x; 2.1480x over previous
//
#include <hip/hip_runtime.h>

// Reduced problem: out[n] depends only on x0 = node_vec[:, :128], emb, W1_l0[:, :, :128],
// b1[:128], W2, b2, W3, b3, W4, b4.  y1/y2/gates are dead code in the reference.
//
// R9 -> R10: SPILL FIX. R9 counters showed VGPR_Count=64 + 43 MB/rep scratch
// writes: __launch_bounds__(1024) let the allocator target 8 waves/EU (64-VGPR
// cap) and spill the whole phase-1 pipeline. __launch_bounds__(1024, 4) = 1
// block/CU, 128-VGPR cap -> no spill, real depth-8 B-ring. Structure = R8.

typedef _Float16 h8 __attribute__((ext_vector_type(8)));
typedef _Float16 h2 __attribute__((ext_vector_type(2)));
typedef float    f32x4 __attribute__((ext_vector_type(4)));
typedef unsigned int u32;

static __device__ __forceinline__ u32 pack2h(float a, float b) {
    h2 t = {(_Float16)a, (_Float16)b};
    return __builtin_bit_cast(u32, t);
}
static __device__ __forceinline__ f32x4 mfma_h(uint4 a, uint4 b, f32x4 c) {
    return __builtin_amdgcn_mfma_f32_16x16x32_f16(
        __builtin_bit_cast(h8, a), __builtin_bit_cast(h8, b), c, 0, 0, 0);
}
// A-frag element j = xh * ee[j];  covers k = q*8 + j for this lane's quad
static __device__ __forceinline__ uint4 mk_afrag(_Float16 xh, const h2* ee) {
    h2 xx = {xh, xh};
    uint4 r;
    r.x = __builtin_bit_cast(u32, (h2)(xx * ee[0]));
    r.y = __builtin_bit_cast(u32, (h2)(xx * ee[1]));
    r.z = __builtin_bit_cast(u32, (h2)(xx * ee[2]));
    r.w = __builtin_bit_cast(u32, (h2)(xx * ee[3]));
    return r;
}

// ---------------------------------------------------------------------------
// Prep: W1_l0 (keep cols 0..127) and W2 -> f16 B-fragment order:
//   W1T[kc][t][lane][j] = f16(W1[K = kc*32 + (lane>>4)*8 + j][t*16 + (lane&15)])
//   W2T[kc][lane][j]    = f16(W2[K][lane&15])
// ---------------------------------------------------------------------------
__global__ __launch_bounds__(256) void prep_kernel(
        const float* __restrict__ W1, const float* __restrict__ W2,
        _Float16* __restrict__ W1T, _Float16* __restrict__ W2T) {
    const int b = blockIdx.x, kc = b >> 2, tp = b & 3;
    const int tid = threadIdx.x;
    __shared__ float l1[32 * 36];
    __shared__ float l2[32 * 20];

    {   // 32 rows x 32 cols sub-tile of W1 (cols tp*32 .. +32)
        int row = tid >> 3, c4 = tid & 7;
        float4 v = *(const float4*)(W1 + (size_t)(kc * 32 + row) * 224 + tp * 32 + c4 * 4);
        *(float4*)(l1 + row * 36 + c4 * 4) = v;
    }
    if (tp == 0 && tid < 128) {
        int row = tid >> 2, c4 = tid & 3;
        float4 v = *(const float4*)(W2 + (size_t)(kc * 32 + row) * 16 + c4 * 4);
        *(float4*)(l2 + row * 20 + c4 * 4) = v;
    }
    __syncthreads();

    if (tid < 128) {
        int tl = tid >> 6, t = tp * 2 + tl, lane = tid & 63;
        int q = lane >> 4, cc = lane & 15, colL = tl * 16 + cc;
        u32 w[4];
#pragma unroll
        for (int jj = 0; jj < 4; ++jj)
            w[jj] = pack2h(l1[(q * 8 + 2 * jj) * 36 + colL],
                           l1[(q * 8 + 2 * jj + 1) * 36 + colL]);
        *(uint4*)(W1T + (size_t)kc * 4096 + (t * 64 + lane) * 8) =
            make_uint4(w[0], w[1], w[2], w[3]);
    }
    if (tp == 0 && tid >= 128 && tid < 192) {
        int lane = tid - 128, q = lane >> 4, cc = lane & 15;
        u32 w[4];
#pragma unroll
        for (int jj = 0; jj < 4; ++jj)
            w[jj] = pack2h(l2[(q * 8 + 2 * jj) * 20 + cc],
                           l2[(q * 8 + 2 * jj + 1) * 20 + cc]);
        *(uint4*)(W2T + (size_t)kc * 512 + lane * 8) = make_uint4(w[0], w[1], w[2], w[3]);
    }
}

// ---------------------------------------------------------------------------
// Main: 64 nodes/block, 16 waves. __launch_bounds__(1024, 4): 1 block/CU,
// 128-VGPR cap -> no spill (R9's 64-cap spilled the pipeline).
// Phase1: wave = (kh = wave>>3 K-half) x (t = wave&7 col-tile);
//   64 nodes x 16 cols x 32 K-steps; kh=1 partials -> LDS -> kh=0 reduces.
// Phase2: wave = (ng = wave>>2 node-group) x (ks = wave&3 K-quarter).
// Phase3: 1024 threads = 64 nodes x 16 cols.
// ---------------------------------------------------------------------------
__global__ __launch_bounds__(1024, 4) void main_kernel(
        const float* __restrict__ node_vec, const float* __restrict__ emb,
        const _Float16* __restrict__ W1T, const _Float16* __restrict__ W2T,
        const float* __restrict__ b1, const float* __restrict__ b2,
        const float* __restrict__ W3, const float* __restrict__ b3,
        const float* __restrict__ W4, const float* __restrict__ b4,
        float* __restrict__ out) {
    __shared__ __align__(16) _Float16 xsh[2 * 4608 + 8];  // even | pad | odd
    __shared__ __align__(16) char     uni[32768];  // p1 partials -> midp+mids
    __shared__ float w3s[256];
    __shared__ float b3s[16];
    __shared__ float w4s[16];
    __shared__ float b4s[1];

    _Float16* xe  = xsh;
    _Float16* xo  = xsh + 4608 + 8;
    float*    part = (float*)uni;                 // 128 cols x 64 nodes f32
    float*    midp = (float*)uni;                 // phase-2 partials
    float*    mids = (float*)(uni + 17408);

    const int tid  = threadIdx.x;
    const int wave = tid >> 6, lane = tid & 63;
    const int q = lane >> 4, c = lane & 15;
    const int ih = q >> 1;            // x-column parity this quad needs
    const int aodd = q & 1;           // emb half this quad needs
    const int nodeBase = blockIdx.x * 64;

    // stage x0 (cols 0..127), split even/odd k-columns, stride 72 halves
    for (int idx = tid; idx < 2048; idx += 1024) {
        int row = idx >> 5, c4 = idx & 31;
        float4 v = *(const float4*)(node_vec + (size_t)(nodeBase + row) * 480 + c4 * 4);
        h2 ev = {(_Float16)v.x, (_Float16)v.z};
        h2 ov = {(_Float16)v.y, (_Float16)v.w};
        *(h2*)(xe + row * 72 + c4 * 2) = ev;
        *(h2*)(xo + row * 72 + c4 * 2) = ov;
    }
    if (tid < 256) w3s[tid] = W3[tid];
    if (tid < 16) { b3s[tid] = b3[tid]; w4s[tid] = W4[tid]; }
    if (tid == 0) b4s[0] = b4[0];

    // per-lane emb slices for all 4 node-groups: node = nodeBase + g*16 + c
    h2 eeg[4][4];
#pragma unroll
    for (int g = 0; g < 4; ++g) {
        const float* ep = emb + (size_t)(nodeBase + g * 16 + c) * 16 + aodd * 8;
        float4 v0 = *(const float4*)ep;
        float4 v1 = *(const float4*)(ep + 4);
        eeg[g][0] = (h2){(_Float16)v0.x, (_Float16)v0.y};
        eeg[g][1] = (h2){(_Float16)v0.z, (_Float16)v0.w};
        eeg[g][2] = (h2){(_Float16)v1.x, (_Float16)v1.y};
        eeg[g][3] = (h2){(_Float16)v1.z, (_Float16)v1.w};
    }
    __syncthreads();

    // ---------------- Phase 1: 64 nodes x 16 cols x 32 K-steps per wave
    const int kh = wave >> 3;                     // K-half
    const int t  = wave & 7;                      // col-tile
    f32x4 acc[4];
#pragma unroll
    for (int g = 0; g < 4; ++g) acc[g] = (f32x4){0.f, 0.f, 0.f, 0.f};

    const uint4* bp = (const uint4*)W1T + t * 64 + lane + kh * 32 * 512;
    const _Float16* xb = (ih ? xo : xe) + kh * 32;
    const _Float16* xr0 = xb + (0 * 16 + c) * 72;
    const _Float16* xr1 = xb + (1 * 16 + c) * 72;
    const _Float16* xr2 = xb + (2 * 16 + c) * 72;
    const _Float16* xr3 = xb + (3 * 16 + c) * 72;

    uint4 ring[8];
#pragma unroll
    for (int r = 0; r < 8; ++r) ring[r] = bp[r * 512];
    h8 xcur[4], xnxt[4];
    xcur[0] = *(const h8*)xr0;       xcur[1] = *(const h8*)xr1;
    xcur[2] = *(const h8*)xr2;       xcur[3] = *(const h8*)xr3;
    xnxt[0] = *(const h8*)(xr0 + 8); xnxt[1] = *(const h8*)(xr1 + 8);
    xnxt[2] = *(const h8*)(xr2 + 8); xnxt[3] = *(const h8*)(xr3 + 8);

#pragma unroll
    for (int bb = 0; bb < 4; ++bb) {
#pragma unroll
        for (int u = 0; u < 8; ++u) {
            const int kl = bb * 8 + u;
            uint4 cur = ring[u];
            ring[u] = bp[(kl + 8) * 512];   // tail reads stay inside W1T+W2T
            acc[0] = mfma_h(mk_afrag(xcur[0][u], eeg[0]), cur, acc[0]);
            acc[1] = mfma_h(mk_afrag(xcur[1][u], eeg[1]), cur, acc[1]);
            acc[2] = mfma_h(mk_afrag(xcur[2][u], eeg[2]), cur, acc[2]);
            acc[3] = mfma_h(mk_afrag(xcur[3][u], eeg[3]), cur, acc[3]);
        }
        xcur[0] = xnxt[0]; xcur[1] = xnxt[1];
        xcur[2] = xnxt[2]; xcur[3] = xnxt[3];
        if (bb + 2 < 4) {
            const int o = (bb + 2) * 8;
            xnxt[0] = *(const h8*)(xr0 + o); xnxt[1] = *(const h8*)(xr1 + o);
            xnxt[2] = *(const h8*)(xr2 + o); xnxt[3] = *(const h8*)(xr3 + o);
        }
    }

    // kh=1 waves publish partials (part region untouched in phase 1)
    if (kh == 1) {
#pragma unroll
        for (int g = 0; g < 4; ++g)
            *(f32x4*)(part + (t * 16 + c) * 64 + g * 16 + q * 4) = acc[g];
    }
    __syncthreads();   // partials visible + all x reads done (before silu overlay)

    // kh=0 waves: reduce, silu -> f16 overlay of x. C layout: col=c, row=q*4+r.
    const float inv2048 = 0.022097086912079608f;   // 1/sqrt(128*16)
    if (kh == 0) {
        float bb1v = b1[t * 16 + c];
        _Float16* dst = (c & 1) ? xo : xe;
        int colh = t * 8 + (c >> 1);
#pragma unroll
        for (int g = 0; g < 4; ++g) {
            f32x4 p = *(const f32x4*)(part + (t * 16 + c) * 64 + g * 16 + q * 4);
#pragma unroll
            for (int r = 0; r < 4; ++r) {
                int node = g * 16 + q * 4 + r;
                float s  = (acc[g][r] + p[r]) * inv2048 + bb1v;
                float sc = s / (1.f + __expf(-s));
                dst[node * 72 + colh] = (_Float16)sc;
            }
        }
    }
    __syncthreads();   // scs ready + part reads done (midp overlays part)

    // ---------------- Phase 2: (silu(s0) (x) emb) @ W2T
    {
        const int ng = wave >> 2, ks = wave & 3;
        const _Float16* srow = (ih ? xo : xe) + (ng * 16 + c) * 72 + ks * 16;
        h8 sa = *(const h8*)srow, sb = *(const h8*)(srow + 8);
        const uint4* b2p = (const uint4*)W2T + lane;
        f32x4 m0 = (f32x4){0.f, 0.f, 0.f, 0.f};
        uint4 wb[4];
#pragma unroll
        for (int u = 0; u < 4; ++u) wb[u] = b2p[(ks * 16 + u) * 64];
#pragma unroll
        for (int k2 = 0; k2 < 16; ++k2) {
            uint4 cur = wb[k2 & 3];
            if (k2 + 4 < 16) wb[k2 & 3] = b2p[(ks * 16 + k2 + 4) * 64];
            _Float16 sv = (k2 < 8) ? sa[k2] : sb[k2 - 8];
            m0 = mfma_h(mk_afrag(sv, eeg[ng]), cur, m0);
        }
#pragma unroll
        for (int r = 0; r < 4; ++r) {
            int node = ng * 16 + q * 4 + r;
            midp[(ks * 64 + node) * 17 + c] = m0[r];
        }
    }
    __syncthreads();

    // reduce 4 K-quarters; 1024 threads = 64 nodes x 16 cols
    {
        int node = tid >> 4, col = tid & 15;
        float m = midp[node * 17 + col] + midp[(64 + node) * 17 + col]
                + midp[(128 + node) * 17 + col] + midp[(192 + node) * 17 + col];
        mids[node * 17 + col] = m * inv2048 + b2[col];
    }
    __syncthreads();

    // ---------------- Phase 3: h = silu(mid@W3/4 + b3); out = h@W4/4 + b4
    {
        int n = tid >> 4, jj = tid & 15;
        float a = 0.f;
#pragma unroll
        for (int cc = 0; cc < 16; ++cc) a += mids[n * 17 + cc] * w3s[cc * 16 + jj];
        a = a * 0.25f + b3s[jj];
        float hh = a / (1.f + __expf(-a));
        float po = hh * w4s[jj];
        po += __shfl_xor(po, 1);
        po += __shfl_xor(po, 2);
        po += __shfl_xor(po, 4);
        po += __shfl_xor(po, 8);
        if (jj == 0) out[nodeBase + n] = po * 0.25f + b4s[0];
    }
}

extern "C" void kernel_launch(void* const* d_in, const int* in_sizes, int n_in,
                              void* d_out, int out_size, void* d_ws, size_t ws_size,
                              hipStream_t stream) {
    const float* node_vec = (const float*)d_in[0];
    const float* emb      = (const float*)d_in[1];
    const float* W1       = (const float*)d_in[2];
    const float* b1v      = (const float*)d_in[5];
    const float* W2       = (const float*)d_in[6];
    const float* b2v      = (const float*)d_in[7];
    const float* W3       = (const float*)d_in[8];
    const float* b3v      = (const float*)d_in[9];
    const float* W4       = (const float*)d_in[10];
    const float* b4v      = (const float*)d_in[11];

    _Float16* W1T = (_Float16*)d_ws;          // 64*4096 halves = 512 KB
    _Float16* W2T = W1T + 64 * 4096;          // 64*512  halves =  64 KB
    float* out = (float*)d_out;

    prep_kernel<<<256, 256, 0, stream>>>(W1, W2, W1T, W2T);
    main_kernel<<<256, 1024, 0, stream>>>(node_vec, emb, W1T, W2T,
                                          b1v, b2v, W3, b3v, W4, b4v, out);
}

// Round 11
// 108.650 us; speedup vs baseline: 2.2392x; 1.0424x over previous
//
#include <hip/hip_runtime.h>

// Reduced problem: out[n] depends only on x0 = node_vec[:, :128], emb, W1_l0[:, :, :128],
// b1[:128], W2, b2, W3, b3, W4, b4.  y1/y2/gates are dead code in the reference.
//
// R10 -> R11: 32x32x16 MFMA for phase 1. One 1KB B-frag now feeds 2 MFMAs
// (2 m-tiles x 32 nodes) at 8 pk_mul -> A-frag VALU per MAC halved, MFMA rate
// up (m119). 16 waves = (kh K-quarter) x (t 32-col tile); cross-kh reduce via
// two f16 LDS partial sets. B traffic unchanged (512 KB/block). (1024,4).

typedef _Float16 h8  __attribute__((ext_vector_type(8)));
typedef _Float16 h2  __attribute__((ext_vector_type(2)));
typedef float    f32x4  __attribute__((ext_vector_type(4)));
typedef float    f32x16 __attribute__((ext_vector_type(16)));
typedef unsigned int u32;

static __device__ __forceinline__ u32 pack2h(float a, float b) {
    h2 t = {(_Float16)a, (_Float16)b};
    return __builtin_bit_cast(u32, t);
}
static __device__ __forceinline__ f32x4 mfma16(uint4 a, uint4 b, f32x4 c) {
    return __builtin_amdgcn_mfma_f32_16x16x32_f16(
        __builtin_bit_cast(h8, a), __builtin_bit_cast(h8, b), c, 0, 0, 0);
}
static __device__ __forceinline__ f32x16 mfma32(uint4 a, uint4 b, f32x16 c) {
    return __builtin_amdgcn_mfma_f32_32x32x16_f16(
        __builtin_bit_cast(h8, a), __builtin_bit_cast(h8, b), c, 0, 0, 0);
}
// A-frag element j = xh * ee[j]
static __device__ __forceinline__ uint4 mk_afrag(_Float16 xh, const h2* ee) {
    h2 xx = {xh, xh};
    uint4 r;
    r.x = __builtin_bit_cast(u32, (h2)(xx * ee[0]));
    r.y = __builtin_bit_cast(u32, (h2)(xx * ee[1]));
    r.z = __builtin_bit_cast(u32, (h2)(xx * ee[2]));
    r.w = __builtin_bit_cast(u32, (h2)(xx * ee[3]));
    return r;
}

// ---------------------------------------------------------------------------
// Prep. Blocks 0..127: W1T in 32x32x16 B-frag order, step = K/16 = x-column i:
//   W1T[step][t][lane][j] = f16(W1[K = step*16 + (lane>>5)*8 + j][t*32 + (lane&31)])
// Blocks 128..191: W2T in 16x16x32 B-frag order (as before):
//   W2T[kc][lane][j] = f16(W2[kc*32 + (lane>>4)*8 + j][lane&15])
// ---------------------------------------------------------------------------
__global__ __launch_bounds__(256) void prep_kernel(
        const float* __restrict__ W1, const float* __restrict__ W2,
        _Float16* __restrict__ W1T, _Float16* __restrict__ W2T) {
    const int tid = threadIdx.x;
    if (blockIdx.x < 128) {
        const int step = blockIdx.x;
        __shared__ float l1[16 * 132];
        for (int idx = tid; idx < 512; idx += 256) {     // 16 rows x 32 float4
            int row = idx >> 5, c4 = idx & 31;
            float4 v = *(const float4*)(W1 + (size_t)(step * 16 + row) * 224 + c4 * 4);
            *(float4*)(l1 + row * 132 + c4 * 4) = v;
        }
        __syncthreads();
        const int t = tid >> 6, lane = tid & 63;
        const int half = lane >> 5, col = t * 32 + (lane & 31);
        u32 w[4];
#pragma unroll
        for (int jj = 0; jj < 4; ++jj)
            w[jj] = pack2h(l1[(half * 8 + 2 * jj) * 132 + col],
                           l1[(half * 8 + 2 * jj + 1) * 132 + col]);
        *(uint4*)(W1T + (size_t)((step * 4 + t) * 64 + lane) * 8) =
            make_uint4(w[0], w[1], w[2], w[3]);
    } else {
        const int kc = blockIdx.x - 128;                 // 0..63
        __shared__ float l2[32 * 20];
        if (tid < 128) {
            int row = tid >> 2, c4 = tid & 3;
            float4 v = *(const float4*)(W2 + (size_t)(kc * 32 + row) * 16 + c4 * 4);
            *(float4*)(l2 + row * 20 + c4 * 4) = v;
        }
        __syncthreads();
        if (tid < 64) {
            int lane = tid, q = lane >> 4, cc = lane & 15;
            u32 w[4];
#pragma unroll
            for (int jj = 0; jj < 4; ++jj)
                w[jj] = pack2h(l2[(q * 8 + 2 * jj) * 20 + cc],
                               l2[(q * 8 + 2 * jj + 1) * 20 + cc]);
            *(uint4*)(W2T + (size_t)kc * 512 + lane * 8) = make_uint4(w[0], w[1], w[2], w[3]);
        }
    }
}

// ---------------------------------------------------------------------------
// Main: 64 nodes/block, 16 waves, (1024,4) -> 1 block/CU, 128-VGPR cap.
// Phase1 (32x32x16): wave = (kh = wave>>2 K-quarter) x (t = wave&3 col-tile);
//   2 m-tiles x 32 nodes x 32 cols x 32 steps; kh partial reduce via 2 f16 sets.
// Phase2 (16x16x32): wave = (ng node-group) x (ks K-quarter), as R8.
// Phase3: 1024 threads.
// LDS: xs/scs 64x136 f16 (17408 B) | sets 2 x 64x136 f16 (34816 B; phase2
// overlays midp+mids here) | w3s/b3s/w4s/b4s.
// ---------------------------------------------------------------------------
__global__ __launch_bounds__(1024, 4) void main_kernel(
        const float* __restrict__ node_vec, const float* __restrict__ emb,
        const _Float16* __restrict__ W1T, const _Float16* __restrict__ W2T,
        const float* __restrict__ b1, const float* __restrict__ b2,
        const float* __restrict__ W3, const float* __restrict__ b3,
        const float* __restrict__ W4, const float* __restrict__ b4,
        float* __restrict__ out) {
    __shared__ __align__(16) _Float16 xs[64 * 136];        // x0 -> later silu(s0)
    __shared__ __align__(16) _Float16 sets[2 * 64 * 136];  // kh partials / midp+mids
    __shared__ float w3s[256];
    __shared__ float b3s[16];
    __shared__ float w4s[16];
    __shared__ float b4s[1];

    _Float16* setA = sets;
    _Float16* setB = sets + 64 * 136;
    float*    midp = (float*)sets;                 // phase >= 2
    float*    mids = (float*)((char*)sets + 17408);

    const int tid  = threadIdx.x;
    const int wave = tid >> 6, lane = tid & 63;
    const int l31 = lane & 31, half = lane >> 5;
    const int nodeBase = blockIdx.x * 64;

    // stage x0 (cols 0..127) f16 row-major, stride 136
    for (int idx = tid; idx < 2048; idx += 1024) {
        int row = idx >> 5, c4 = idx & 31;
        float4 v = *(const float4*)(node_vec + (size_t)(nodeBase + row) * 480 + c4 * 4);
        u32 p0 = pack2h(v.x, v.y), p1 = pack2h(v.z, v.w);
        *(uint2*)(xs + row * 136 + c4 * 4) = make_uint2(p0, p1);
    }
    if (tid < 256) w3s[tid] = W3[tid];
    if (tid < 16) { b3s[tid] = b3[tid]; w4s[tid] = W4[tid]; }
    if (tid == 0) b4s[0] = b4[0];

    // phase-1 emb slices: m-tile mt node = nodeBase + mt*32 + l31, a = half*8 + j
    h2 ee0[4], ee1[4];
#pragma unroll
    for (int mt = 0; mt < 2; ++mt) {
        const float* ep = emb + (size_t)(nodeBase + mt * 32 + l31) * 16 + half * 8;
        float4 v0 = *(const float4*)ep;
        float4 v1 = *(const float4*)(ep + 4);
        h2* ee = mt ? ee1 : ee0;
        ee[0] = (h2){(_Float16)v0.x, (_Float16)v0.y};
        ee[1] = (h2){(_Float16)v0.z, (_Float16)v0.w};
        ee[2] = (h2){(_Float16)v1.x, (_Float16)v1.y};
        ee[3] = (h2){(_Float16)v1.z, (_Float16)v1.w};
    }
    __syncthreads();

    // ---------------- Phase 1: 64 nodes x 32 cols x 32 steps (K/16) per wave
    const int kh = wave >> 2;                      // K-quarter (32 steps)
    const int t  = wave & 3;                       // 32-col tile
    f32x16 acc0 = {0.f}, acc1 = {0.f};
#pragma unroll
    for (int r = 0; r < 16; ++r) { acc0[r] = 0.f; acc1[r] = 0.f; }

    const uint4* bp = (const uint4*)W1T + ((kh * 32 * 4 + t) * 64 + lane);
    const _Float16* xr0 = xs + (0 * 32 + l31) * 136 + kh * 32;
    const _Float16* xr1 = xs + (1 * 32 + l31) * 136 + kh * 32;

    uint4 ring[8];
#pragma unroll
    for (int r = 0; r < 8; ++r) ring[r] = bp[r * 256];
    h8 xc0, xc1, xn0, xn1;
    xc0 = *(const h8*)xr0;       xc1 = *(const h8*)xr1;
    xn0 = *(const h8*)(xr0 + 8); xn1 = *(const h8*)(xr1 + 8);

#pragma unroll
    for (int bb = 0; bb < 4; ++bb) {
#pragma unroll
        for (int u = 0; u < 8; ++u) {
            uint4 cur = ring[u];
            ring[u] = bp[(bb * 8 + u + 8) * 256];  // tail stays inside W1T+W2T
            acc0 = mfma32(mk_afrag(xc0[u], ee0), cur, acc0);
            acc1 = mfma32(mk_afrag(xc1[u], ee1), cur, acc1);
        }
        xc0 = xn0; xc1 = xn1;
        if (bb + 2 < 4) {
            xn0 = *(const h8*)(xr0 + (bb + 2) * 8);
            xn1 = *(const h8*)(xr1 + (bb + 2) * 8);
        }
    }

    // C layout (32x32): col = t*32 + l31, row = (r&3) + 8*(r>>2) + 4*half
    const int colG = t * 32 + l31;
#define ROWOF(r) (((r) & 3) + 8 * ((r) >> 2) + 4 * half)

    // kh reduction: kh=2 -> setA, kh=3 -> setB
    if (kh >= 2) {
        _Float16* st = (kh == 2) ? setA : setB;
#pragma unroll
        for (int r = 0; r < 16; ++r) {
            int row = ROWOF(r);
            st[(row)      * 136 + colG] = (_Float16)acc0[r];
            st[(row + 32) * 136 + colG] = (_Float16)acc1[r];
        }
    }
    __syncthreads();
    if (kh < 2) {
        const _Float16* st = (kh == 0) ? setA : setB;
#pragma unroll
        for (int r = 0; r < 16; ++r) {
            int row = ROWOF(r);
            acc0[r] += (float)st[(row)      * 136 + colG];
            acc1[r] += (float)st[(row + 32) * 136 + colG];
        }
    }
    __syncthreads();
    if (kh == 1) {
#pragma unroll
        for (int r = 0; r < 16; ++r) {
            int row = ROWOF(r);
            setA[(row)      * 136 + colG] = (_Float16)acc0[r];
            setA[(row + 32) * 136 + colG] = (_Float16)acc1[r];
        }
    }
    __syncthreads();

    // kh=0: final reduce + silu -> scs (overlays xs; all x reads done)
    const float inv2048 = 0.022097086912079608f;   // 1/sqrt(128*16)
    if (kh == 0) {
        float bb1v = b1[colG];
#pragma unroll
        for (int r = 0; r < 16; ++r) {
            int row = ROWOF(r);
            float s0 = (acc0[r] + (float)setA[(row)      * 136 + colG]) * inv2048 + bb1v;
            float s1 = (acc1[r] + (float)setA[(row + 32) * 136 + colG]) * inv2048 + bb1v;
            xs[(row)      * 136 + colG] = (_Float16)(s0 / (1.f + __expf(-s0)));
            xs[(row + 32) * 136 + colG] = (_Float16)(s1 / (1.f + __expf(-s1)));
        }
    }
    __syncthreads();   // scs ready; sets free for midp overlay

    // ---------------- Phase 2: (silu(s0) (x) emb) @ W2T  (16x16x32, as R8)
    {
        const int ng = wave >> 2, ks = wave & 3;
        const int q = lane >> 4, c = lane & 15;
        const int ih = q >> 1, aodd = q & 1;
        h2 ee[4];
        {
            const float* ep = emb + (size_t)(nodeBase + ng * 16 + c) * 16 + aodd * 8;
            float4 v0 = *(const float4*)ep;
            float4 v1 = *(const float4*)(ep + 4);
            ee[0] = (h2){(_Float16)v0.x, (_Float16)v0.y};
            ee[1] = (h2){(_Float16)v0.z, (_Float16)v0.w};
            ee[2] = (h2){(_Float16)v1.x, (_Float16)v1.y};
            ee[3] = (h2){(_Float16)v1.z, (_Float16)v1.w};
        }
        const _Float16* srow = xs + (ng * 16 + c) * 136;   // col = 2*k2global + ih
        const uint4* b2p = (const uint4*)W2T + lane;
        f32x4 m0 = (f32x4){0.f, 0.f, 0.f, 0.f};
        uint4 wb[4];
#pragma unroll
        for (int u = 0; u < 4; ++u) wb[u] = b2p[(ks * 16 + u) * 64];
#pragma unroll
        for (int k2 = 0; k2 < 16; ++k2) {
            uint4 cur = wb[k2 & 3];
            if (k2 + 4 < 16) wb[k2 & 3] = b2p[(ks * 16 + k2 + 4) * 64];
            _Float16 sv = srow[(ks * 16 + k2) * 2 + ih];
            m0 = mfma16(mk_afrag(sv, ee), cur, m0);
        }
#pragma unroll
        for (int r = 0; r < 4; ++r) {
            int node = ng * 16 + q * 4 + r;
            midp[(ks * 64 + node) * 17 + c] = m0[r];
        }
    }
    __syncthreads();

    // reduce 4 K-quarters; 1024 threads = 64 nodes x 16 cols
    {
        int node = tid >> 4, col = tid & 15;
        float m = midp[node * 17 + col] + midp[(64 + node) * 17 + col]
                + midp[(128 + node) * 17 + col] + midp[(192 + node) * 17 + col];
        mids[node * 17 + col] = m * inv2048 + b2[col];
    }
    __syncthreads();

    // ---------------- Phase 3: h = silu(mid@W3/4 + b3); out = h@W4/4 + b4
    {
        int n = tid >> 4, jj = tid & 15;
        float a = 0.f;
#pragma unroll
        for (int cc = 0; cc < 16; ++cc) a += mids[n * 17 + cc] * w3s[cc * 16 + jj];
        a = a * 0.25f + b3s[jj];
        float hh = a / (1.f + __expf(-a));
        float po = hh * w4s[jj];
        po += __shfl_xor(po, 1);
        po += __shfl_xor(po, 2);
        po += __shfl_xor(po, 4);
        po += __shfl_xor(po, 8);
        if (jj == 0) out[nodeBase + n] = po * 0.25f + b4s[0];
    }
#undef ROWOF
}

extern "C" void kernel_launch(void* const* d_in, const int* in_sizes, int n_in,
                              void* d_out, int out_size, void* d_ws, size_t ws_size,
                              hipStream_t stream) {
    const float* node_vec = (const float*)d_in[0];
    const float* emb      = (const float*)d_in[1];
    const float* W1       = (const float*)d_in[2];
    const float* b1v      = (const float*)d_in[5];
    const float* W2       = (const float*)d_in[6];
    const float* b2v      = (const float*)d_in[7];
    const float* W3       = (const float*)d_in[8];
    const float* b3v      = (const float*)d_in[9];
    const float* W4       = (const float*)d_in[10];
    const float* b4v      = (const float*)d_in[11];

    _Float16* W1T = (_Float16*)d_ws;          // 128*4*64*8 halves = 512 KB
    _Float16* W2T = W1T + 128 * 4 * 64 * 8;   // 64*512 halves = 64 KB
    float* out = (float*)d_out;

    prep_kernel<<<192, 256, 0, stream>>>(W1, W2, W1T, W2T);
    main_kernel<<<256, 1024, 0, stream>>>(node_vec, emb, W1T, W2T,
                                          b1v, b2v, W3, b3v, W4, b4v, out);
}